// Round 1
// baseline (468.078 us; speedup 1.0000x reference)
//
#include <hip/hip_runtime.h>
#include <stdint.h>

#define BB 16
#define CC 2048
#define DD 256
#define MM (BB*CC)

typedef __attribute__((ext_vector_type(4))) float f32x4;
typedef __attribute__((ext_vector_type(8))) short bf16x8;
typedef __attribute__((ext_vector_type(4))) short s16x4;

static __device__ __forceinline__ short f2bf(float f) {
  union { float f; uint32_t u; } v; v.f = f;
  uint32_t u = v.u;
  return (short)((u + 0x7FFFu + ((u >> 16) & 1u)) >> 16);
}

// ---------------------------------------------------------------------------
// Kernel 1: gather compact cos/sin from the (sparse) dense rotary matrix R.
// cs[pos][k] = (R[pos,2k,2k], R[pos,2k+1,2k])
// ---------------------------------------------------------------------------
__global__ __launch_bounds__(256) void k_cs(const float* __restrict__ R,
                                            float2* __restrict__ cs) {
  int id = blockIdx.x * 256 + threadIdx.x;     // C*128 threads
  int pos = id >> 7, k = id & 127;
  size_t base = (size_t)pos * DD * DD + (size_t)(2 * k) * DD + 2 * k;
  cs[id] = make_float2(R[base], R[base + DD]);
}

// ---------------------------------------------------------------------------
// Kernel 2: fused QKV projection (bf16 MFMA, x-tile shared across 3 weights)
// + RoPE on q,k in the epilogue (pair partner via shfl_xor(1)).
// q is pre-scaled by 1/sqrt(D). Outputs bf16.
// ---------------------------------------------------------------------------
__global__ __launch_bounds__(256) void k_qkv(
    const float* __restrict__ x,
    const float* __restrict__ Wq, const float* __restrict__ bq,
    const float* __restrict__ Wk, const float* __restrict__ bk,
    const float* __restrict__ Wv, const float* __restrict__ bv,
    const float2* __restrict__ cs,
    short* __restrict__ q_rot, short* __restrict__ k_rot,
    short* __restrict__ v_out)
{
  __shared__ short xs[64 * DD];   // 32 KB, rows 512B, XOR-swizzled (row&7)<<4
  __shared__ short wsh[DD * 32];  // 16 KB, rows 64B,  XOR-swizzled (e&3)<<4
  const int t = threadIdx.x;
  const int lane = t & 63, w = t >> 6;
  const int g = lane >> 4, li = lane & 15;
  const int m0 = blockIdx.x * 64;

  // stage x tile (f32 -> bf16), swizzled
  #pragma unroll
  for (int i = 0; i < 16; ++i) {
    int chunk = i * 256 + t;               // 4096 chunks of 4 f32
    int row = chunk >> 6, c4 = chunk & 63;
    f32x4 xv = *(const f32x4*)(x + (size_t)(m0 + row) * DD + c4 * 4);
    s16x4 b4;
    b4[0] = f2bf(xv[0]); b4[1] = f2bf(xv[1]); b4[2] = f2bf(xv[2]); b4[3] = f2bf(xv[3]);
    *(s16x4*)((char*)xs + row * 512 + ((c4 * 8) ^ ((row & 7) << 4))) = b4;
  }

  const float* Wm[3] = {Wq, Wk, Wv};
  const float* bm[3] = {bq, bk, bv};
  short* dm[3] = {q_rot, k_rot, v_out};

  for (int mat = 0; mat < 3; ++mat) {
    f32x4 zero4 = {0.f, 0.f, 0.f, 0.f};
    f32x4 acc[16];
    #pragma unroll
    for (int nt = 0; nt < 16; ++nt) acc[nt] = zero4;

    for (int kc = 0; kc < 8; ++kc) {
      __syncthreads();                     // previous chunk's reads done
      // stage W[:, kc*32 .. +32] (f32 -> bf16), swizzled
      #pragma unroll
      for (int i = 0; i < 8; ++i) {
        int chunk = i * 256 + t;           // 2048 chunks of 4 f32
        int e = chunk >> 3, c4 = chunk & 7;
        f32x4 wv = *(const f32x4*)(Wm[mat] + (size_t)e * DD + kc * 32 + c4 * 4);
        s16x4 b4;
        b4[0] = f2bf(wv[0]); b4[1] = f2bf(wv[1]); b4[2] = f2bf(wv[2]); b4[3] = f2bf(wv[3]);
        *(s16x4*)((char*)wsh + e * 64 + ((c4 * 8) ^ ((e & 3) << 4))) = b4;
      }
      __syncthreads();

      const int arow = w * 16 + li;
      bf16x8 a = *(const bf16x8*)((char*)xs + arow * 512 +
                                  (((kc * 64) + g * 16) ^ ((arow & 7) << 4)));
      #pragma unroll
      for (int nt = 0; nt < 16; ++nt) {
        int e = nt * 16 + li;
        bf16x8 bf = *(const bf16x8*)((char*)wsh + e * 64 +
                                     ((g * 16) ^ ((e & 3) << 4)));
        acc[nt] = __builtin_amdgcn_mfma_f32_16x16x32_bf16(a, bf, acc[nt], 0, 0, 0);
      }
    }

    // epilogue: bias, RoPE (q,k), scale (q), store bf16
    short* dst = dm[mat];
    #pragma unroll
    for (int nt = 0; nt < 16; ++nt) {
      int e = nt * 16 + li;
      float bias = bm[mat][e];
      #pragma unroll
      for (int r = 0; r < 4; ++r) {
        int m = m0 + w * 16 + g * 4 + r;
        float val = acc[nt][r] + bias;
        if (mat < 2) {
          float other = __shfl_xor(val, 1);        // pair partner (e^1)
          float2 csv = cs[(size_t)(m & (CC - 1)) * 128 + (e >> 1)];
          val = csv.x * val + ((e & 1) ? csv.y * other : -csv.y * other);
          if (mat == 0) val *= 0.0625f;            // 1/sqrt(D) folded into q
        }
        dst[(size_t)m * DD + e] = f2bf(val);
      }
    }
  }
}

// ---------------------------------------------------------------------------
// Kernel 3: transpose v (b,c,d) -> v_t (b,d,c) through a padded LDS tile.
// ---------------------------------------------------------------------------
__global__ __launch_bounds__(256) void k_tr(const short* __restrict__ v_in,
                                            short* __restrict__ v_t) {
  __shared__ short T[64 * 65];
  const int t = threadIdx.x;
  const int bid = blockIdx.x;                // 32 * 4 * 16 blocks
  const int ct = bid & 31, dt = (bid >> 5) & 3, b = bid >> 7;
  const int c0 = ct * 64, d0 = dt * 64;
  #pragma unroll
  for (int i = 0; i < 4; ++i) {
    int chunk = i * 256 + t;                 // 1024 chunks of 4 shorts
    int c = chunk >> 4, d4 = (chunk & 15) * 4;
    s16x4 v = *(const s16x4*)(v_in + ((size_t)(b * CC + c0 + c)) * DD + d0 + d4);
    T[c * 65 + d4 + 0] = v[0]; T[c * 65 + d4 + 1] = v[1];
    T[c * 65 + d4 + 2] = v[2]; T[c * 65 + d4 + 3] = v[3];
  }
  __syncthreads();
  #pragma unroll
  for (int i = 0; i < 4; ++i) {
    int chunk = i * 256 + t;
    int d = chunk >> 4, c4 = (chunk & 15) * 4;
    s16x4 o;
    o[0] = T[(c4 + 0) * 65 + d]; o[1] = T[(c4 + 1) * 65 + d];
    o[2] = T[(c4 + 2) * 65 + d]; o[3] = T[(c4 + 3) * 65 + d];
    *(s16x4*)(v_t + ((size_t)(b * DD + d0 + d)) * CC + c0 + c4) = o;
  }
}

// ---------------------------------------------------------------------------
// Kernel 4: causal flash attention. 256 blocks (1/CU), 4 waves, each block =
// one batch + a balanced pair of 64-row q-tiles (qt, 31-qt) => constant work.
// K/V tiles staged in XOR-swizzled LDS; online softmax; P via per-wave LDS.
// ---------------------------------------------------------------------------
__global__ __launch_bounds__(256) void k_attn(
    const short* __restrict__ q_rot, const short* __restrict__ k_rot,
    const short* __restrict__ v_t, float* __restrict__ out)
{
  __shared__ short Ks[64 * DD];   // [kv=64][d=256] bf16, rows 512B, swz (row&7)<<4
  __shared__ short Vs[DD * 64];   // [d=256][kv=64] bf16, rows 128B, swz (d&7)<<4
  __shared__ short Ps[4][16 * 80];// per-wave P [q=16][kv=64(+pad)] rows 160B
  const int t = threadIdx.x;
  const int lane = t & 63, w = t >> 6;
  const int g = lane >> 4, li = lane & 15;

  // XCD-aware decode: XCD p%8 owns batches {2x, 2x+1} -> K/V stays in its L2.
  const int p = blockIdx.x;
  const int xcd = p & 7, slot = p >> 3;
  const int b = 2 * xcd + (slot >> 4);
  const int j = slot & 15;

  for (int item = 0; item < 2; ++item) {
    const int qt = item ? j : (31 - j);    // heavy tile first; pair sums to 33
    const int q0 = qt * 64;
    const int qrow = q0 + w * 16 + li;
    const short* qbase = q_rot + ((size_t)b * CC + qrow) * DD;
    bf16x8 qf[8];
    #pragma unroll
    for (int dc = 0; dc < 8; ++dc)
      qf[dc] = *(const bf16x8*)(qbase + dc * 32 + g * 8);

    f32x4 zero4 = {0.f, 0.f, 0.f, 0.f};
    f32x4 O[16];
    #pragma unroll
    for (int i = 0; i < 16; ++i) O[i] = zero4;
    float mrow[4], lrow[4];
    #pragma unroll
    for (int r = 0; r < 4; ++r) { mrow[r] = -__builtin_inff(); lrow[r] = 0.f; }

    for (int kt = 0; kt <= qt; ++kt) {
      const int k0 = kt * 64;
      __syncthreads();                     // all waves done reading LDS
      // stage K tile (swizzled)
      #pragma unroll
      for (int i = 0; i < 8; ++i) {
        int chunk = i * 256 + t;           // 2048 x 16B
        int row = chunk >> 5, o = chunk & 31;
        int4 kv4 = *(const int4*)(k_rot + ((size_t)b * CC + k0 + row) * DD + o * 8);
        *(int4*)((char*)Ks + row * 512 + ((o * 16) ^ ((row & 7) << 4))) = kv4;
      }
      // stage V^T tile (swizzled)
      #pragma unroll
      for (int i = 0; i < 8; ++i) {
        int chunk = i * 256 + t;           // 2048 x 16B
        int d = chunk >> 3, o = chunk & 7;
        int4 vv4 = *(const int4*)(v_t + ((size_t)b * DD + d) * CC + k0 + o * 8);
        *(int4*)((char*)Vs + d * 128 + ((o * 16) ^ ((d & 7) << 4))) = vv4;
      }
      __syncthreads();

      // S = Q K^T  (scale already folded into q)
      f32x4 S[4];
      #pragma unroll
      for (int nt = 0; nt < 4; ++nt) S[nt] = zero4;
      #pragma unroll
      for (int dc = 0; dc < 8; ++dc) {
        #pragma unroll
        for (int nt = 0; nt < 4; ++nt) {
          int krow = nt * 16 + li;
          bf16x8 kf = *(const bf16x8*)((char*)Ks + krow * 512 +
                                       (((dc * 64) + g * 16) ^ ((krow & 7) << 4)));
          S[nt] = __builtin_amdgcn_mfma_f32_16x16x32_bf16(qf[dc], kf, S[nt], 0, 0, 0);
        }
      }

      // online softmax (per q-row; rows live in 16-lane groups)
      const bool last_tile = (kt == qt);
      #pragma unroll
      for (int r = 0; r < 4; ++r) {
        const int qr = q0 + w * 16 + g * 4 + r;
        float mx = -__builtin_inff();
        #pragma unroll
        for (int nt = 0; nt < 4; ++nt) {
          float s = S[nt][r];
          if (last_tile && (k0 + nt * 16 + li) > qr) s = -__builtin_inff();
          S[nt][r] = s;
          mx = fmaxf(mx, s);
        }
        mx = fmaxf(mx, __shfl_xor(mx, 1));
        mx = fmaxf(mx, __shfl_xor(mx, 2));
        mx = fmaxf(mx, __shfl_xor(mx, 4));
        mx = fmaxf(mx, __shfl_xor(mx, 8));
        const float mnew = fmaxf(mrow[r], mx);
        const float alpha = __expf(mrow[r] - mnew);   // exp(-inf)=0 on 1st tile
        mrow[r] = mnew;
        float rsum = 0.f;
        #pragma unroll
        for (int nt = 0; nt < 4; ++nt) {
          float pv = __expf(S[nt][r] - mnew);         // masked -> exp(-inf)=0
          S[nt][r] = pv;
          rsum += pv;
        }
        rsum += __shfl_xor(rsum, 1);
        rsum += __shfl_xor(rsum, 2);
        rsum += __shfl_xor(rsum, 4);
        rsum += __shfl_xor(rsum, 8);
        lrow[r] = lrow[r] * alpha + rsum;
        #pragma unroll
        for (int dt2 = 0; dt2 < 16; ++dt2) O[dt2][r] *= alpha;
      }

      // P (C-layout) -> per-wave LDS (bf16, swizzled) -> A-frags
      #pragma unroll
      for (int nt = 0; nt < 4; ++nt) {
        #pragma unroll
        for (int r = 0; r < 4; ++r) {
          int prow = g * 4 + r;
          *(short*)((char*)Ps[w] + prow * 160 +
                    (((nt * 16 + li) * 2) ^ ((prow & 3) << 4))) = f2bf(S[nt][r]);
        }
      }

      // O += P V
      #pragma unroll
      for (int kc = 0; kc < 2; ++kc) {
        bf16x8 pf = *(const bf16x8*)((char*)Ps[w] + li * 160 +
                                     (((kc * 64) + g * 16) ^ ((li & 3) << 4)));
        #pragma unroll
        for (int dt2 = 0; dt2 < 16; ++dt2) {
          int vrow = dt2 * 16 + li;
          bf16x8 vf = *(const bf16x8*)((char*)Vs + vrow * 128 +
                                       (((kc * 64) + g * 16) ^ ((vrow & 7) << 4)));
          O[dt2] = __builtin_amdgcn_mfma_f32_16x16x32_bf16(pf, vf, O[dt2], 0, 0, 0);
        }
      }
    } // kt

    // epilogue: normalize and store f32
    float invl[4];
    #pragma unroll
    for (int r = 0; r < 4; ++r) invl[r] = 1.f / lrow[r];
    #pragma unroll
    for (int dt2 = 0; dt2 < 16; ++dt2) {
      #pragma unroll
      for (int r = 0; r < 4; ++r) {
        int qr = q0 + w * 16 + g * 4 + r;
        out[((size_t)b * CC + qr) * DD + dt2 * 16 + li] = O[dt2][r] * invl[r];
      }
    }
  } // item
}

// ---------------------------------------------------------------------------
extern "C" void kernel_launch(void* const* d_in, const int* in_sizes, int n_in,
                              void* d_out, int out_size, void* d_ws, size_t ws_size,
                              hipStream_t stream) {
  const float* x  = (const float*)d_in[0];
  const float* Wq = (const float*)d_in[1];
  const float* bq = (const float*)d_in[2];
  const float* Wk = (const float*)d_in[3];
  const float* bk = (const float*)d_in[4];
  const float* Wv = (const float*)d_in[5];
  const float* bv = (const float*)d_in[6];
  const float* R  = (const float*)d_in[7];
  float* out = (float*)d_out;
  (void)in_sizes; (void)n_in; (void)out_size; (void)ws_size;

  // ws layout: cs table 2MB | q_rot 16MB | k_rot 16MB | v 16MB | v_t 16MB  (~66MB)
  char* ws = (char*)d_ws;
  float2* cs   = (float2*)ws;
  short* q_rot = (short*)(ws + (2u << 20));
  short* k_rot = q_rot + (size_t)MM * DD;
  short* v_buf = k_rot + (size_t)MM * DD;
  short* v_tr  = v_buf + (size_t)MM * DD;

  k_cs  <<<1024, 256, 0, stream>>>(R, cs);
  k_qkv <<< 512, 256, 0, stream>>>(x, Wq, bq, Wk, bk, Wv, bv, cs, q_rot, k_rot, v_buf);
  k_tr  <<<2048, 256, 0, stream>>>(v_buf, v_tr);
  k_attn<<< 256, 256, 0, stream>>>(q_rot, k_rot, v_tr, out);
}

// Round 2
// 329.500 us; speedup vs baseline: 1.4206x; 1.4206x over previous
//
#include <hip/hip_runtime.h>
#include <stdint.h>

#define BB 16
#define CC 2048
#define DD 256
#define MM (BB*CC)

typedef __attribute__((ext_vector_type(4))) float f32x4;
typedef __attribute__((ext_vector_type(8))) short bf16x8;
typedef __attribute__((ext_vector_type(4))) short s16x4;

static __device__ __forceinline__ short f2bf(float f) {
  union { float f; uint32_t u; } v; v.f = f;
  uint32_t u = v.u;
  return (short)((u + 0x7FFFu + ((u >> 16) & 1u)) >> 16);
}

// async global->LDS, 16B per lane, dest = uniform base + lane*16
#define GLDS16(gp, lp) __builtin_amdgcn_global_load_lds(                      \
    (const __attribute__((address_space(1))) void*)(gp),                      \
    (__attribute__((address_space(3))) void*)(lp), 16, 0, 0)

// ---------------------------------------------------------------------------
// Kernel 1: gather compact cos/sin from the (sparse) dense rotary matrix R.
// cs[pos][k] = (R[pos,2k,2k], R[pos,2k+1,2k])
// ---------------------------------------------------------------------------
__global__ __launch_bounds__(256) void k_cs(const float* __restrict__ R,
                                            float2* __restrict__ cs) {
  int id = blockIdx.x * 256 + threadIdx.x;     // C*128 threads
  int pos = id >> 7, k = id & 127;
  size_t base = (size_t)pos * DD * DD + (size_t)(2 * k) * DD + 2 * k;
  cs[id] = make_float2(R[base], R[base + DD]);
}

// ---------------------------------------------------------------------------
// Kernel 2: fused QKV projection (bf16 MFMA, x-tile shared across 3 weights)
// + RoPE on q,k in the epilogue; v written DIRECTLY TRANSPOSED to v_t[b][d][c]
// (C-fragment rows are contiguous in c -> free 8B stores; kills k_tr).
// q is pre-scaled by 1/sqrt(D). Outputs bf16.
// ---------------------------------------------------------------------------
__global__ __launch_bounds__(256) void k_qkv(
    const float* __restrict__ x,
    const float* __restrict__ Wq, const float* __restrict__ bq,
    const float* __restrict__ Wk, const float* __restrict__ bk,
    const float* __restrict__ Wv, const float* __restrict__ bv,
    const float2* __restrict__ cs,
    short* __restrict__ q_rot, short* __restrict__ k_rot,
    short* __restrict__ v_t)
{
  __shared__ short xs[64 * DD];   // 32 KB, rows 512B, XOR-swizzled (row&7)<<4
  __shared__ short wsh[DD * 32];  // 16 KB, rows 64B,  XOR-swizzled (e&3)<<4
  const int t = threadIdx.x;
  const int lane = t & 63, w = t >> 6;
  const int g = lane >> 4, li = lane & 15;
  const int m0 = blockIdx.x * 64;

  // stage x tile (f32 -> bf16), swizzled
  #pragma unroll
  for (int i = 0; i < 16; ++i) {
    int chunk = i * 256 + t;               // 4096 chunks of 4 f32
    int row = chunk >> 6, c4 = chunk & 63;
    f32x4 xv = *(const f32x4*)(x + (size_t)(m0 + row) * DD + c4 * 4);
    s16x4 b4;
    b4[0] = f2bf(xv[0]); b4[1] = f2bf(xv[1]); b4[2] = f2bf(xv[2]); b4[3] = f2bf(xv[3]);
    *(s16x4*)((char*)xs + row * 512 + ((c4 * 8) ^ ((row & 7) << 4))) = b4;
  }

  const float* Wm[3] = {Wq, Wk, Wv};
  const float* bm[3] = {bq, bk, bv};
  short* dm[2] = {q_rot, k_rot};

  for (int mat = 0; mat < 3; ++mat) {
    f32x4 zero4 = {0.f, 0.f, 0.f, 0.f};
    f32x4 acc[16];
    #pragma unroll
    for (int nt = 0; nt < 16; ++nt) acc[nt] = zero4;

    for (int kc = 0; kc < 8; ++kc) {
      __syncthreads();                     // previous chunk's reads done
      // stage W[:, kc*32 .. +32] (f32 -> bf16), swizzled
      #pragma unroll
      for (int i = 0; i < 8; ++i) {
        int chunk = i * 256 + t;           // 2048 chunks of 4 f32
        int e = chunk >> 3, c4 = chunk & 7;
        f32x4 wv = *(const f32x4*)(Wm[mat] + (size_t)e * DD + kc * 32 + c4 * 4);
        s16x4 b4;
        b4[0] = f2bf(wv[0]); b4[1] = f2bf(wv[1]); b4[2] = f2bf(wv[2]); b4[3] = f2bf(wv[3]);
        *(s16x4*)((char*)wsh + e * 64 + ((c4 * 8) ^ ((e & 3) << 4))) = b4;
      }
      __syncthreads();

      const int arow = w * 16 + li;
      bf16x8 a = *(const bf16x8*)((char*)xs + arow * 512 +
                                  (((kc * 64) + g * 16) ^ ((arow & 7) << 4)));
      #pragma unroll
      for (int nt = 0; nt < 16; ++nt) {
        int e = nt * 16 + li;
        bf16x8 bf = *(const bf16x8*)((char*)wsh + e * 64 +
                                     ((g * 16) ^ ((e & 3) << 4)));
        acc[nt] = __builtin_amdgcn_mfma_f32_16x16x32_bf16(a, bf, acc[nt], 0, 0, 0);
      }
    }

    // epilogue
    if (mat < 2) {
      short* dst = dm[mat];
      #pragma unroll
      for (int nt = 0; nt < 16; ++nt) {
        int e = nt * 16 + li;
        float bias = bm[mat][e];
        #pragma unroll
        for (int r = 0; r < 4; ++r) {
          int m = m0 + w * 16 + g * 4 + r;
          float val = acc[nt][r] + bias;
          float other = __shfl_xor(val, 1);        // pair partner (e^1)
          float2 csv = cs[(size_t)(m & (CC - 1)) * 128 + (e >> 1)];
          val = csv.x * val + ((e & 1) ? csv.y * other : -csv.y * other);
          if (mat == 0) val *= 0.0625f;            // 1/sqrt(D) folded into q
          dst[(size_t)m * DD + e] = f2bf(val);
        }
      }
    } else {
      // v, transposed: v_t[(b*DD + e)*CC + c], r-contiguous -> 8B stores
      const int bb = m0 >> 11, c0 = m0 & (CC - 1);
      const int cc = c0 + w * 16 + g * 4;
      #pragma unroll
      for (int nt = 0; nt < 16; ++nt) {
        int e = nt * 16 + li;
        float bias = bv[e];
        s16x4 o4;
        #pragma unroll
        for (int r = 0; r < 4; ++r) o4[r] = f2bf(acc[nt][r] + bias);
        *(s16x4*)(v_t + ((size_t)(bb * DD + e)) * CC + cc) = o4;
      }
    }
  }
}

// ---------------------------------------------------------------------------
// Kernel 3: causal flash attention. 512 blocks (2/CU), 4 waves, each block =
// one 64-row q-tile. Complement pairing: blocks j and j+256 share a batch and
// have qt summing to 31 (balanced CU makespan), heavy tiles dispatch first.
// K/V staged via global_load_lds with pre-swizzled source; defer-max softmax.
// ---------------------------------------------------------------------------
__global__ __launch_bounds__(256, 2) void k_attn(
    const short* __restrict__ q_rot, const short* __restrict__ k_rot,
    const short* __restrict__ v_t, float* __restrict__ out)
{
  __shared__ short Ks[64 * DD];   // [kv=64][d=256] bf16, rows 512B, swz (row&7)<<4
  __shared__ short Vs[DD * 64];   // [d=256][kv=64] bf16, rows 128B, swz (d&7)<<4
  __shared__ short Ps[4][16 * 80];// per-wave P [q=16][kv=64(+pad)] rows 160B
  const int t = threadIdx.x;
  const int lane = t & 63, w = t >> 6;
  const int g = lane >> 4, li = lane & 15;

  // XCD p%8 owns batches {2x,2x+1}; s<32 heavy half, s>=32 complement half.
  const int p = blockIdx.x;
  const int xcd = p & 7, s = p >> 3;
  const int s2 = (s < 32) ? s : (s - 32);
  const int qt = (s < 32) ? (31 - (s2 >> 1)) : (s2 >> 1);
  const int b = 2 * xcd + (s2 & 1);

  const int q0 = qt * 64;
  const int qrow = q0 + w * 16 + li;
  const short* qbase = q_rot + ((size_t)b * CC + qrow) * DD;
  bf16x8 qf[8];
  #pragma unroll
  for (int dc = 0; dc < 8; ++dc)
    qf[dc] = *(const bf16x8*)(qbase + dc * 32 + g * 8);

  f32x4 zero4 = {0.f, 0.f, 0.f, 0.f};
  f32x4 O[16];
  #pragma unroll
  for (int i = 0; i < 16; ++i) O[i] = zero4;
  float mrow[4], lrow[4];
  #pragma unroll
  for (int r = 0; r < 4; ++r) { mrow[r] = -__builtin_inff(); lrow[r] = 0.f; }

  const short* kbase = k_rot + (size_t)b * CC * DD;
  const short* vbase = v_t + (size_t)b * DD * CC;

  for (int kt = 0; kt <= qt; ++kt) {
    const int k0 = kt * 64;
    __syncthreads();                     // all waves done reading LDS
    // stage K tile: linear LDS dest, inverse-swizzled global source
    #pragma unroll
    for (int i = 0; i < 8; ++i) {
      int c = i * 4 + w;                 // 1KB chunk
      int row = 2 * c + (lane >> 5);
      int cb = (lane & 31) * 16;
      const char* src = (const char*)(kbase + (size_t)(k0 + row) * DD) +
                        (cb ^ ((row & 7) << 4));
      GLDS16(src, (char*)Ks + c * 1024);
    }
    // stage V^T tile
    #pragma unroll
    for (int i = 0; i < 8; ++i) {
      int c = i * 4 + w;
      int d = 8 * c + (lane >> 3);
      int cb = (lane & 7) * 16;
      const char* src = (const char*)(vbase + (size_t)d * CC + k0) +
                        (cb ^ ((d & 7) << 4));
      GLDS16(src, (char*)Vs + c * 1024);
    }
    __syncthreads();                     // drains vmcnt -> LDS ready

    // S = Q K^T  (scale already folded into q)
    f32x4 S[4];
    #pragma unroll
    for (int nt = 0; nt < 4; ++nt) S[nt] = zero4;
    __builtin_amdgcn_s_setprio(1);
    #pragma unroll
    for (int dc = 0; dc < 8; ++dc) {
      #pragma unroll
      for (int nt = 0; nt < 4; ++nt) {
        int krow = nt * 16 + li;
        bf16x8 kf = *(const bf16x8*)((char*)Ks + krow * 512 +
                                     (((dc * 64) + g * 16) ^ ((krow & 7) << 4)));
        S[nt] = __builtin_amdgcn_mfma_f32_16x16x32_bf16(qf[dc], kf, S[nt], 0, 0, 0);
      }
    }
    __builtin_amdgcn_s_setprio(0);

    // causal mask only on the diagonal tile (uniform branch)
    if (kt == qt) {
      #pragma unroll
      for (int nt = 0; nt < 4; ++nt) {
        #pragma unroll
        for (int r = 0; r < 4; ++r) {
          if ((k0 + nt * 16 + li) > (q0 + w * 16 + g * 4 + r))
            S[nt][r] = -__builtin_inff();
        }
      }
    }

    // online softmax with defer-max (THR=8): skip rescale when max ~flat
    float mxr[4];
    #pragma unroll
    for (int r = 0; r < 4; ++r) {
      float mx = fmaxf(fmaxf(S[0][r], S[1][r]), fmaxf(S[2][r], S[3][r]));
      mx = fmaxf(mx, __shfl_xor(mx, 1));
      mx = fmaxf(mx, __shfl_xor(mx, 2));
      mx = fmaxf(mx, __shfl_xor(mx, 4));
      mx = fmaxf(mx, __shfl_xor(mx, 8));
      mxr[r] = mx;
    }
    int need = 0;
    #pragma unroll
    for (int r = 0; r < 4; ++r) need |= (mxr[r] > mrow[r] + 8.f) ? 1 : 0;
    if (__any(need)) {
      #pragma unroll
      for (int r = 0; r < 4; ++r) {
        float mnew = fmaxf(mrow[r], mxr[r]);
        float al = __expf(mrow[r] - mnew);   // exp(-inf)=0 on first tile
        mrow[r] = mnew;
        lrow[r] *= al;
        #pragma unroll
        for (int dt2 = 0; dt2 < 16; ++dt2) O[dt2][r] *= al;
      }
    }
    #pragma unroll
    for (int r = 0; r < 4; ++r) {
      float rsum = 0.f;
      #pragma unroll
      for (int nt = 0; nt < 4; ++nt) {
        float pv = __expf(S[nt][r] - mrow[r]);   // masked -> 0; bounded e^8
        S[nt][r] = pv;
        rsum += pv;
      }
      rsum += __shfl_xor(rsum, 1);
      rsum += __shfl_xor(rsum, 2);
      rsum += __shfl_xor(rsum, 4);
      rsum += __shfl_xor(rsum, 8);
      lrow[r] += rsum;
    }

    // P (C-layout) -> per-wave LDS (bf16, swizzled) -> A-frags
    #pragma unroll
    for (int nt = 0; nt < 4; ++nt) {
      #pragma unroll
      for (int r = 0; r < 4; ++r) {
        int prow = g * 4 + r;
        *(short*)((char*)Ps[w] + prow * 160 +
                  (((nt * 16 + li) * 2) ^ ((prow & 3) << 4))) = f2bf(S[nt][r]);
      }
    }

    // O += P V
    __builtin_amdgcn_s_setprio(1);
    #pragma unroll
    for (int kc = 0; kc < 2; ++kc) {
      bf16x8 pf = *(const bf16x8*)((char*)Ps[w] + li * 160 +
                                   (((kc * 64) + g * 16) ^ ((li & 3) << 4)));
      #pragma unroll
      for (int dt2 = 0; dt2 < 16; ++dt2) {
        int vrow = dt2 * 16 + li;
        bf16x8 vf = *(const bf16x8*)((char*)Vs + vrow * 128 +
                                     (((kc * 64) + g * 16) ^ ((vrow & 7) << 4)));
        O[dt2] = __builtin_amdgcn_mfma_f32_16x16x32_bf16(pf, vf, O[dt2], 0, 0, 0);
      }
    }
    __builtin_amdgcn_s_setprio(0);
  } // kt

  // epilogue: normalize and store f32
  float invl[4];
  #pragma unroll
  for (int r = 0; r < 4; ++r) invl[r] = 1.f / lrow[r];
  #pragma unroll
  for (int dt2 = 0; dt2 < 16; ++dt2) {
    #pragma unroll
    for (int r = 0; r < 4; ++r) {
      int qr = q0 + w * 16 + g * 4 + r;
      out[((size_t)b * CC + qr) * DD + dt2 * 16 + li] = O[dt2][r] * invl[r];
    }
  }
}

// ---------------------------------------------------------------------------
extern "C" void kernel_launch(void* const* d_in, const int* in_sizes, int n_in,
                              void* d_out, int out_size, void* d_ws, size_t ws_size,
                              hipStream_t stream) {
  const float* x  = (const float*)d_in[0];
  const float* Wq = (const float*)d_in[1];
  const float* bq = (const float*)d_in[2];
  const float* Wk = (const float*)d_in[3];
  const float* bk = (const float*)d_in[4];
  const float* Wv = (const float*)d_in[5];
  const float* bv = (const float*)d_in[6];
  const float* R  = (const float*)d_in[7];
  float* out = (float*)d_out;
  (void)in_sizes; (void)n_in; (void)out_size; (void)ws_size;

  // ws layout: cs table 2MB | q_rot 16MB | k_rot 16MB | v_t 16MB  (~50MB)
  char* ws = (char*)d_ws;
  float2* cs   = (float2*)ws;
  short* q_rot = (short*)(ws + (2u << 20));
  short* k_rot = q_rot + (size_t)MM * DD;
  short* v_tr  = k_rot + (size_t)MM * DD;

  k_cs  <<<1024, 256, 0, stream>>>(R, cs);
  k_qkv <<< 512, 256, 0, stream>>>(x, Wq, bq, Wk, bk, Wv, bv, cs, q_rot, k_rot, v_tr);
  k_attn<<< 512, 256, 0, stream>>>(q_rot, k_rot, v_tr, out);
}

// Round 3
// 272.478 us; speedup vs baseline: 1.7179x; 1.2093x over previous
//
#include <hip/hip_runtime.h>
#include <stdint.h>

#define BB 16
#define CC 2048
#define DD 256
#define MM (BB*CC)

typedef __attribute__((ext_vector_type(4))) float f32x4;
typedef __attribute__((ext_vector_type(8))) short bf16x8;
typedef __attribute__((ext_vector_type(4))) short s16x4;

static __device__ __forceinline__ short f2bf(float f) {
  union { float f; uint32_t u; } v; v.f = f;
  uint32_t u = v.u;
  return (short)((u + 0x7FFFu + ((u >> 16) & 1u)) >> 16);
}

// async global->LDS, 16B per lane, dest = uniform base + lane*16
#define GLDS16(gp, lp) __builtin_amdgcn_global_load_lds(                      \
    (const __attribute__((address_space(1))) void*)(gp),                      \
    (__attribute__((address_space(3))) void*)(lp), 16, 0, 0)

// ---------------------------------------------------------------------------
// Kernel 1: gather compact cos/sin from the (sparse) dense rotary matrix R.
// ---------------------------------------------------------------------------
__global__ __launch_bounds__(256) void k_cs(const float* __restrict__ R,
                                            float2* __restrict__ cs) {
  int id = blockIdx.x * 256 + threadIdx.x;     // C*128 threads
  int pos = id >> 7, k = id & 127;
  size_t base = (size_t)pos * DD * DD + (size_t)(2 * k) * DD + 2 * k;
  cs[id] = make_float2(R[base], R[base + DD]);
}

// ---------------------------------------------------------------------------
// Kernel 2: fused QKV projection + RoPE; v written directly transposed.
// W-chunk f32 loads are issued AFTER the second barrier (overlap MFMA),
// written to LDS next iteration -> per-kc load latency hidden.
// ---------------------------------------------------------------------------
__global__ __launch_bounds__(256) void k_qkv(
    const float* __restrict__ x,
    const float* __restrict__ Wq, const float* __restrict__ bq,
    const float* __restrict__ Wk, const float* __restrict__ bk,
    const float* __restrict__ Wv, const float* __restrict__ bv,
    const float2* __restrict__ cs,
    short* __restrict__ q_rot, short* __restrict__ k_rot,
    short* __restrict__ v_t)
{
  __shared__ short xs[64 * DD];   // 32 KB, rows 512B, swz (row&7)<<4
  __shared__ short wsh[DD * 32];  // 16 KB, rows 64B,  swz (e&3)<<4
  const int t = threadIdx.x;
  const int lane = t & 63, w = t >> 6;
  const int g = lane >> 4, li = lane & 15;
  const int m0 = blockIdx.x * 64;

  // stage x tile (f32 -> bf16), swizzled
  #pragma unroll
  for (int i = 0; i < 16; ++i) {
    int chunk = i * 256 + t;               // 4096 chunks of 4 f32
    int row = chunk >> 6, c4 = chunk & 63;
    f32x4 xv = *(const f32x4*)(x + (size_t)(m0 + row) * DD + c4 * 4);
    s16x4 b4;
    b4[0] = f2bf(xv[0]); b4[1] = f2bf(xv[1]); b4[2] = f2bf(xv[2]); b4[3] = f2bf(xv[3]);
    *(s16x4*)((char*)xs + row * 512 + ((c4 * 8) ^ ((row & 7) << 4))) = b4;
  }

  const float* Wm[3] = {Wq, Wk, Wv};
  const float* bm[3] = {bq, bk, bv};
  short* dm[2] = {q_rot, k_rot};

  #pragma unroll
  for (int mat = 0; mat < 3; ++mat) {
    f32x4 zero4 = {0.f, 0.f, 0.f, 0.f};
    f32x4 acc[16];
    #pragma unroll
    for (int nt = 0; nt < 16; ++nt) acc[nt] = zero4;

    f32x4 wreg[8];                         // prefetched W chunk (kc=0)
    #pragma unroll
    for (int i = 0; i < 8; ++i) {
      int chunk = i * 256 + t;
      int e = chunk >> 3, c4 = chunk & 7;
      wreg[i] = *(const f32x4*)(Wm[mat] + (size_t)e * DD + c4 * 4);
    }

    #pragma unroll
    for (int kc = 0; kc < 8; ++kc) {
      __syncthreads();                     // readers of previous chunk done
      #pragma unroll
      for (int i = 0; i < 8; ++i) {
        int chunk = i * 256 + t;
        int e = chunk >> 3, c4 = chunk & 7;
        s16x4 b4;
        b4[0] = f2bf(wreg[i][0]); b4[1] = f2bf(wreg[i][1]);
        b4[2] = f2bf(wreg[i][2]); b4[3] = f2bf(wreg[i][3]);
        *(s16x4*)((char*)wsh + e * 64 + ((c4 * 8) ^ ((e & 3) << 4))) = b4;
      }
      __syncthreads();
      if (kc < 7) {                        // issue next chunk under the MFMAs
        #pragma unroll
        for (int i = 0; i < 8; ++i) {
          int chunk = i * 256 + t;
          int e = chunk >> 3, c4 = chunk & 7;
          wreg[i] = *(const f32x4*)(Wm[mat] + (size_t)e * DD + (kc + 1) * 32 + c4 * 4);
        }
      }
      const int arow = w * 16 + li;
      bf16x8 a = *(const bf16x8*)((char*)xs + arow * 512 +
                                  (((kc * 64) + g * 16) ^ ((arow & 7) << 4)));
      #pragma unroll
      for (int nt = 0; nt < 16; ++nt) {
        int e = nt * 16 + li;
        bf16x8 bf = *(const bf16x8*)((char*)wsh + e * 64 +
                                     ((g * 16) ^ ((e & 3) << 4)));
        acc[nt] = __builtin_amdgcn_mfma_f32_16x16x32_bf16(a, bf, acc[nt], 0, 0, 0);
      }
    }

    // epilogue
    if (mat < 2) {
      short* dst = dm[mat];
      #pragma unroll
      for (int nt = 0; nt < 16; ++nt) {
        int e = nt * 16 + li;
        float bias = bm[mat][e];
        #pragma unroll
        for (int r = 0; r < 4; ++r) {
          int m = m0 + w * 16 + g * 4 + r;
          float val = acc[nt][r] + bias;
          float other = __shfl_xor(val, 1);        // pair partner (e^1)
          float2 csv = cs[(size_t)(m & (CC - 1)) * 128 + (e >> 1)];
          val = csv.x * val + ((e & 1) ? csv.y * other : -csv.y * other);
          if (mat == 0) val *= 0.0625f;            // 1/sqrt(D) folded into q
          dst[(size_t)m * DD + e] = f2bf(val);
        }
      }
    } else {
      // v, transposed: v_t[(b*DD + e)*CC + c], r-contiguous -> 8B stores
      const int bb = m0 >> 11, c0 = m0 & (CC - 1);
      const int cc = c0 + w * 16 + g * 4;
      #pragma unroll
      for (int nt = 0; nt < 16; ++nt) {
        int e = nt * 16 + li;
        float bias = bv[e];
        s16x4 o4;
        #pragma unroll
        for (int r = 0; r < 4; ++r) o4[r] = f2bf(acc[nt][r] + bias);
        *(s16x4*)(v_t + ((size_t)(bb * DD + e)) * CC + cc) = o4;
      }
    }
  }
}

// ---------------------------------------------------------------------------
// Kernel 3: causal flash attention. 256 blocks (1/CU), 4 waves, QBLK=128
// (32 rows/wave as 2 row-blocks -> K/V fragments reused, LDS traffic halved).
// Double-buffered K/V staged via global_load_lds with counted vmcnt (16),
// raw s_barrier (no full drain). Defer-max softmax.
// ---------------------------------------------------------------------------
__global__ __launch_bounds__(256, 1) void k_attn(
    const short* __restrict__ q_rot, const short* __restrict__ k_rot,
    const short* __restrict__ v_t, float* __restrict__ out)
{
  __shared__ short Ks[2][64 * DD];   // 2 x 32KB, rows 512B, swz (row&7)<<4
  __shared__ short Vs[2][DD * 64];   // 2 x 32KB, rows 128B, swz (d&7)<<4
  __shared__ short Ps[4][32 * 80];   // per-wave P [32 q][64 kv(+pad)] 160B rows
  const int t = threadIdx.x;
  const int lane = t & 63, w = t >> 6;
  const int g = lane >> 4, li = lane & 15;

  // XCD p%8 owns batches {2x,2x+1} -> K/V (4MB) stays in its L2.
  const int p = blockIdx.x;
  const int xcd = p & 7, s = p >> 3;          // s: 0..31
  const int b = 2 * xcd + (s & 1);
  const int qt = s >> 1;                      // 0..15
  const int q0 = qt * 128;
  const int NT = 2 * qt + 2;                  // kv tiles of 64

  const short* kbase = k_rot + (size_t)b * CC * DD;
  const short* vbase = v_t + (size_t)b * DD * CC;

  // Q fragments: rows q0 + w*32 + rb*16 + li
  bf16x8 qf[2][8];
  #pragma unroll
  for (int rb = 0; rb < 2; ++rb) {
    const short* qb = q_rot + ((size_t)b * CC + q0 + w * 32 + rb * 16 + li) * DD;
    #pragma unroll
    for (int dc = 0; dc < 8; ++dc)
      qf[rb][dc] = *(const bf16x8*)(qb + dc * 32 + g * 8);
  }
  asm volatile("s_waitcnt vmcnt(0)" ::: "memory");   // clean slate for counting
  __builtin_amdgcn_sched_barrier(0);

  f32x4 zero4 = {0.f, 0.f, 0.f, 0.f};
  f32x4 O[2][16];
  #pragma unroll
  for (int rb = 0; rb < 2; ++rb)
    #pragma unroll
    for (int i = 0; i < 16; ++i) O[rb][i] = zero4;
  float mrow[2][4], lrow[2][4];
  #pragma unroll
  for (int rb = 0; rb < 2; ++rb)
    #pragma unroll
    for (int r = 0; r < 4; ++r) { mrow[rb][r] = -__builtin_inff(); lrow[rb][r] = 0.f; }

  auto STAGE = [&](int buf, int kt) {           // 16 GLDS16 per wave
    const int k0s = kt * 64;
    #pragma unroll
    for (int i = 0; i < 8; ++i) {
      int c = i * 4 + w;
      int row = 2 * c + (lane >> 5);
      int cb = (lane & 31) * 16;
      const char* src = (const char*)(kbase + (size_t)(k0s + row) * DD) +
                        (cb ^ ((row & 7) << 4));
      GLDS16(src, (char*)(&Ks[buf][0]) + c * 1024);
    }
    #pragma unroll
    for (int i = 0; i < 8; ++i) {
      int c = i * 4 + w;
      int d = 8 * c + (lane >> 3);
      int cb = (lane & 7) * 16;
      const char* src = (const char*)(vbase + (size_t)d * CC + k0s) +
                        (cb ^ ((d & 7) << 4));
      GLDS16(src, (char*)(&Vs[buf][0]) + c * 1024);
    }
  };

  int cur = 0;
  STAGE(0, 0);
  for (int kt = 0; kt < NT; ++kt) {
    const int k0 = kt * 64;
    if (kt + 1 < NT) {
      STAGE(cur ^ 1, kt + 1);                  // prefetch next tile
      asm volatile("s_waitcnt vmcnt(16)" ::: "memory");   // current tile ready
    } else {
      asm volatile("s_waitcnt vmcnt(0)" ::: "memory");
    }
    __builtin_amdgcn_sched_barrier(0);
    __builtin_amdgcn_s_barrier();              // all waves' stages landed

    // S = Q K^T (scale folded into q); kf reused for both row-blocks
    f32x4 S[2][4];
    #pragma unroll
    for (int rb = 0; rb < 2; ++rb)
      #pragma unroll
      for (int nt = 0; nt < 4; ++nt) S[rb][nt] = zero4;
    __builtin_amdgcn_s_setprio(1);
    #pragma unroll
    for (int dc = 0; dc < 8; ++dc) {
      #pragma unroll
      for (int nt = 0; nt < 4; ++nt) {
        int krow = nt * 16 + li;
        bf16x8 kf = *(const bf16x8*)((char*)(&Ks[cur][0]) + krow * 512 +
                                     (((dc * 64) + g * 16) ^ ((krow & 7) << 4)));
        S[0][nt] = __builtin_amdgcn_mfma_f32_16x16x32_bf16(qf[0][dc], kf, S[0][nt], 0, 0, 0);
        S[1][nt] = __builtin_amdgcn_mfma_f32_16x16x32_bf16(qf[1][dc], kf, S[1][nt], 0, 0, 0);
      }
    }
    __builtin_amdgcn_s_setprio(0);

    // causal mask only near the diagonal (last two kv tiles of this block)
    if (kt >= NT - 2) {
      #pragma unroll
      for (int rb = 0; rb < 2; ++rb)
        #pragma unroll
        for (int nt = 0; nt < 4; ++nt)
          #pragma unroll
          for (int r = 0; r < 4; ++r)
            if ((k0 + nt * 16 + li) > (q0 + w * 32 + rb * 16 + g * 4 + r))
              S[rb][nt][r] = -__builtin_inff();
    }

    // online softmax with defer-max (THR=8)
    float mxr[2][4];
    #pragma unroll
    for (int rb = 0; rb < 2; ++rb)
      #pragma unroll
      for (int r = 0; r < 4; ++r) {
        float mx = fmaxf(fmaxf(S[rb][0][r], S[rb][1][r]), fmaxf(S[rb][2][r], S[rb][3][r]));
        mx = fmaxf(mx, __shfl_xor(mx, 1));
        mx = fmaxf(mx, __shfl_xor(mx, 2));
        mx = fmaxf(mx, __shfl_xor(mx, 4));
        mx = fmaxf(mx, __shfl_xor(mx, 8));
        mxr[rb][r] = mx;
      }
    int need = 0;
    #pragma unroll
    for (int rb = 0; rb < 2; ++rb)
      #pragma unroll
      for (int r = 0; r < 4; ++r) need |= (mxr[rb][r] > mrow[rb][r] + 8.f) ? 1 : 0;
    if (__any(need)) {
      #pragma unroll
      for (int rb = 0; rb < 2; ++rb)
        #pragma unroll
        for (int r = 0; r < 4; ++r) {
          float mnew = fmaxf(mrow[rb][r], mxr[rb][r]);
          float al = __expf(mrow[rb][r] - mnew);
          mrow[rb][r] = mnew;
          lrow[rb][r] *= al;
          #pragma unroll
          for (int dt2 = 0; dt2 < 16; ++dt2) O[rb][dt2][r] *= al;
        }
    }
    #pragma unroll
    for (int rb = 0; rb < 2; ++rb)
      #pragma unroll
      for (int r = 0; r < 4; ++r) {
        float rsum = 0.f;
        #pragma unroll
        for (int nt = 0; nt < 4; ++nt) {
          float pv = __expf(S[rb][nt][r] - mrow[rb][r]);
          S[rb][nt][r] = pv;
          rsum += pv;
        }
        rsum += __shfl_xor(rsum, 1);
        rsum += __shfl_xor(rsum, 2);
        rsum += __shfl_xor(rsum, 4);
        rsum += __shfl_xor(rsum, 8);
        lrow[rb][r] += rsum;
      }

    // P (C-layout) -> per-wave LDS (bf16, swizzled by row&3)
    #pragma unroll
    for (int rb = 0; rb < 2; ++rb)
      #pragma unroll
      for (int nt = 0; nt < 4; ++nt)
        #pragma unroll
        for (int r = 0; r < 4; ++r) {
          int pr = rb * 16 + g * 4 + r;
          *(short*)((char*)(&Ps[w][0]) + pr * 160 +
                    (((nt * 16 + li) * 2) ^ ((pr & 3) << 4))) = f2bf(S[rb][nt][r]);
        }

    // O += P V ; vf reused for both row-blocks
    __builtin_amdgcn_s_setprio(1);
    #pragma unroll
    for (int kc = 0; kc < 2; ++kc) {
      bf16x8 pf0 = *(const bf16x8*)((char*)(&Ps[w][0]) + li * 160 +
                                    (((kc * 64) + g * 16) ^ ((li & 3) << 4)));
      bf16x8 pf1 = *(const bf16x8*)((char*)(&Ps[w][0]) + (16 + li) * 160 +
                                    (((kc * 64) + g * 16) ^ ((li & 3) << 4)));
      #pragma unroll
      for (int dt2 = 0; dt2 < 16; ++dt2) {
        int vrow = dt2 * 16 + li;
        bf16x8 vf = *(const bf16x8*)((char*)(&Vs[cur][0]) + vrow * 128 +
                                     (((kc * 64) + g * 16) ^ ((vrow & 7) << 4)));
        O[0][dt2] = __builtin_amdgcn_mfma_f32_16x16x32_bf16(pf0, vf, O[0][dt2], 0, 0, 0);
        O[1][dt2] = __builtin_amdgcn_mfma_f32_16x16x32_bf16(pf1, vf, O[1][dt2], 0, 0, 0);
      }
    }
    __builtin_amdgcn_s_setprio(0);
    __builtin_amdgcn_s_barrier();          // readers done before next restage
    cur ^= 1;
  } // kt

  // epilogue: normalize and store f32
  #pragma unroll
  for (int rb = 0; rb < 2; ++rb) {
    float invl[4];
    #pragma unroll
    for (int r = 0; r < 4; ++r) invl[r] = 1.f / lrow[rb][r];
    #pragma unroll
    for (int dt2 = 0; dt2 < 16; ++dt2)
      #pragma unroll
      for (int r = 0; r < 4; ++r) {
        int qr = q0 + w * 32 + rb * 16 + g * 4 + r;
        out[((size_t)b * CC + qr) * DD + dt2 * 16 + li] = O[rb][dt2][r] * invl[r];
      }
  }
}

// ---------------------------------------------------------------------------
extern "C" void kernel_launch(void* const* d_in, const int* in_sizes, int n_in,
                              void* d_out, int out_size, void* d_ws, size_t ws_size,
                              hipStream_t stream) {
  const float* x  = (const float*)d_in[0];
  const float* Wq = (const float*)d_in[1];
  const float* bq = (const float*)d_in[2];
  const float* Wk = (const float*)d_in[3];
  const float* bk = (const float*)d_in[4];
  const float* Wv = (const float*)d_in[5];
  const float* bv = (const float*)d_in[6];
  const float* R  = (const float*)d_in[7];
  float* out = (float*)d_out;
  (void)in_sizes; (void)n_in; (void)out_size; (void)ws_size;

  // ws layout: cs table 2MB | q_rot 16MB | k_rot 16MB | v_t 16MB  (~50MB)
  char* ws = (char*)d_ws;
  float2* cs   = (float2*)ws;
  short* q_rot = (short*)(ws + (2u << 20));
  short* k_rot = q_rot + (size_t)MM * DD;
  short* v_tr  = k_rot + (size_t)MM * DD;

  k_cs  <<<1024, 256, 0, stream>>>(R, cs);
  k_qkv <<< 512, 256, 0, stream>>>(x, Wq, bq, Wk, bk, Wv, bv, cs, q_rot, k_rot, v_tr);
  k_attn<<< 256, 256, 0, stream>>>(q_rot, k_rot, v_tr, out);
}

// Round 4
// 245.350 us; speedup vs baseline: 1.9078x; 1.1106x over previous
//
#include <hip/hip_runtime.h>
#include <stdint.h>

#define BB 16
#define CC 2048
#define DD 256
#define MM (BB*CC)

typedef __attribute__((ext_vector_type(4))) float f32x4;
typedef __attribute__((ext_vector_type(8))) short bf16x8;
typedef __attribute__((ext_vector_type(4))) short s16x4;

static __device__ __forceinline__ short f2bf(float f) {
  union { float f; uint32_t u; } v; v.f = f;
  uint32_t u = v.u;
  return (short)((u + 0x7FFFu + ((u >> 16) & 1u)) >> 16);
}

// async global->LDS, 16B per lane, dest = uniform base + lane*16
#define GLDS16(gp, lp) __builtin_amdgcn_global_load_lds(                      \
    (const __attribute__((address_space(1))) void*)(gp),                      \
    (__attribute__((address_space(3))) void*)(lp), 16, 0, 0)

// ---------------------------------------------------------------------------
// Kernel 1: compute cos/sin table on device (fp64) -- no reads of dense R.
// cs[pos][k] = (cos(pos*theta_k), sin(pos*theta_k)), theta_k = 10000^((1-k)/128)
// ---------------------------------------------------------------------------
__global__ __launch_bounds__(256) void k_trig(float2* __restrict__ cs) {
  int id = blockIdx.x * 256 + threadIdx.x;     // CC*128 threads
  int pos = id >> 7, k = id & 127;
  double th = pow(10000.0, (1.0 - (double)k) / 128.0);
  double ang = (double)pos * th;
  cs[id] = make_float2((float)cos(ang), (float)sin(ang));
}

// ---------------------------------------------------------------------------
// Kernel 2: convert W{q,k,v} f32 -> bf16, laid out in the exact linear order
// k_qkv's global_load_lds staging consumes (per-kc 16KB blocks, pre-swizzled).
// LDS target layout within a mat: offset o = e*64 + ((c4*8) ^ ((e&3)<<4)).
// ---------------------------------------------------------------------------
__global__ __launch_bounds__(256) void k_wconv(
    const float* __restrict__ Wq, const float* __restrict__ Wk,
    const float* __restrict__ Wv, short* __restrict__ wb) {
  int gid = blockIdx.x * 256 + threadIdx.x;    // 49152 groups of 8B
  int mat = gid / 16384;
  int rem = gid & 16383;
  int kc = rem >> 11;            // 2048 8B-groups per 16KB block
  int o  = (rem & 2047) * 8;     // byte offset in block
  int e  = o >> 6;
  int c4 = ((o & 63) ^ ((e & 3) << 4)) >> 3;
  const float* W = (mat == 0) ? Wq : (mat == 1) ? Wk : Wv;
  f32x4 wv = *(const f32x4*)(W + (size_t)e * DD + kc * 32 + c4 * 4);
  s16x4 b4;
  b4[0] = f2bf(wv[0]); b4[1] = f2bf(wv[1]); b4[2] = f2bf(wv[2]); b4[3] = f2bf(wv[3]);
  *(s16x4*)((char*)wb + (size_t)gid * 8) = b4;
}

// ---------------------------------------------------------------------------
// Kernel 3: fused QKV projection + RoPE; v written directly transposed.
// All 3 mats' W K-slice staged together per kc via GLDS16 from wb
// (48 MFMA between barrier pairs). 80KB LDS -> 2 blocks/CU.
// ---------------------------------------------------------------------------
__global__ __launch_bounds__(256, 2) void k_qkv(
    const float* __restrict__ x, const short* __restrict__ wb,
    const float* __restrict__ bq, const float* __restrict__ bk,
    const float* __restrict__ bv, const float2* __restrict__ cs,
    short* __restrict__ q_rot, short* __restrict__ k_rot,
    short* __restrict__ v_t)
{
  __shared__ short xs[64 * DD];     // 32 KB, rows 512B, swz (row&7)<<4
  __shared__ short wsh[3 * 8192];   // 48 KB = 3 mats x 16KB per-kc slice
  const int t = threadIdx.x;
  const int lane = t & 63, w = t >> 6;
  const int g = lane >> 4, li = lane & 15;
  const int m0 = blockIdx.x * 64;

  // stage x tile (f32 -> bf16), swizzled
  #pragma unroll
  for (int i = 0; i < 16; ++i) {
    int chunk = i * 256 + t;
    int row = chunk >> 6, c4 = chunk & 63;
    f32x4 xv = *(const f32x4*)(x + (size_t)(m0 + row) * DD + c4 * 4);
    s16x4 b4;
    b4[0] = f2bf(xv[0]); b4[1] = f2bf(xv[1]); b4[2] = f2bf(xv[2]); b4[3] = f2bf(xv[3]);
    *(s16x4*)((char*)xs + row * 512 + ((c4 * 8) ^ ((row & 7) << 4))) = b4;
  }
  __syncthreads();

  f32x4 zero4 = {0.f, 0.f, 0.f, 0.f};
  f32x4 accQ[16], accK[16], accV[16];
  #pragma unroll
  for (int nt = 0; nt < 16; ++nt) { accQ[nt] = zero4; accK[nt] = zero4; accV[nt] = zero4; }

  for (int kc = 0; kc < 8; ++kc) {
    // stage this kc's W slice for all 3 mats: 48 chunks of 1KB
    #pragma unroll
    for (int i = 0; i < 12; ++i) {
      int cc = i * 4 + w;
      const char* src = (const char*)wb + ((cc >> 4) * 131072) + (kc * 16384) +
                        ((cc & 15) * 1024) + lane * 16;
      GLDS16(src, (char*)wsh + cc * 1024);
    }
    asm volatile("s_waitcnt vmcnt(0)" ::: "memory");
    __builtin_amdgcn_sched_barrier(0);
    __builtin_amdgcn_s_barrier();

    const int arow = w * 16 + li;
    bf16x8 a = *(const bf16x8*)((char*)xs + arow * 512 +
                                (((kc * 64) + g * 16) ^ ((arow & 7) << 4)));
    #pragma unroll
    for (int nt = 0; nt < 16; ++nt) {
      int e = nt * 16 + li;
      int off = e * 64 + ((g * 16) ^ ((e & 3) << 4));
      bf16x8 fq = *(const bf16x8*)((char*)wsh + off);
      bf16x8 fk = *(const bf16x8*)((char*)wsh + 16384 + off);
      bf16x8 fv = *(const bf16x8*)((char*)wsh + 32768 + off);
      accQ[nt] = __builtin_amdgcn_mfma_f32_16x16x32_bf16(a, fq, accQ[nt], 0, 0, 0);
      accK[nt] = __builtin_amdgcn_mfma_f32_16x16x32_bf16(a, fk, accK[nt], 0, 0, 0);
      accV[nt] = __builtin_amdgcn_mfma_f32_16x16x32_bf16(a, fv, accV[nt], 0, 0, 0);
    }
    __builtin_amdgcn_s_barrier();         // readers done before next restage
  }

  // epilogues: q,k with RoPE; v transposed
  #pragma unroll
  for (int nt = 0; nt < 16; ++nt) {
    int e = nt * 16 + li;
    float bQ = bq[e], bK = bk[e];
    #pragma unroll
    for (int r = 0; r < 4; ++r) {
      int m = m0 + w * 16 + g * 4 + r;
      float2 csv = cs[(size_t)(m & (CC - 1)) * 128 + (e >> 1)];
      float vq = accQ[nt][r] + bQ;
      float oq = __shfl_xor(vq, 1);
      vq = csv.x * vq + ((e & 1) ? csv.y * oq : -csv.y * oq);
      q_rot[(size_t)m * DD + e] = f2bf(vq * 0.0625f);   // 1/sqrt(D) folded
      float vk = accK[nt][r] + bK;
      float ok = __shfl_xor(vk, 1);
      vk = csv.x * vk + ((e & 1) ? csv.y * ok : -csv.y * ok);
      k_rot[(size_t)m * DD + e] = f2bf(vk);
    }
  }
  {
    const int bb = m0 >> 11, c0 = m0 & (CC - 1);
    const int ccol = c0 + w * 16 + g * 4;
    #pragma unroll
    for (int nt = 0; nt < 16; ++nt) {
      int e = nt * 16 + li;
      float bias = bv[e];
      s16x4 o4;
      #pragma unroll
      for (int r = 0; r < 4; ++r) o4[r] = f2bf(accV[nt][r] + bias);
      *(s16x4*)(v_t + ((size_t)(bb * DD + e)) * CC + ccol) = o4;
    }
  }
}

// ---------------------------------------------------------------------------
// Kernel 4: causal flash attention. 512 blocks x 128 threads (2 waves),
// QBLK=64 (32 rows/wave as 2 row-blocks), KVBLK=32, dbuf K/V via GLDS16
// with counted vmcnt. 69KB LDS -> 2 blocks/CU; blocks p and p+256 land on
// the same CU with complementary qt (sum 31), same batch & XCD.
// ---------------------------------------------------------------------------
__global__ __launch_bounds__(128, 2) void k_attn(
    const short* __restrict__ q_rot, const short* __restrict__ k_rot,
    const short* __restrict__ v_t, float* __restrict__ out)
{
  __shared__ short Ks[2][32 * DD];   // 2 x 16KB, rows 512B, swz (row&7)<<4
  __shared__ short Vs[2][DD * 32];   // 2 x 16KB, rows 64B,  swz (d&3)<<4
  __shared__ short Ps[2][32 * 40];   // per-wave P [32 q][32 kv + pad] 80B rows
  const int t = threadIdx.x;
  const int lane = t & 63, w = t >> 6;          // w: 0..1
  const int g = lane >> 4, li = lane & 15;

  const int p = blockIdx.x;
  const int xcd = p & 7, s = p >> 3;            // s: 0..63
  const int idx = (s < 32) ? (s >> 1) : ((s - 32) >> 1);
  const int qt = (s < 32) ? (31 - idx) : idx;   // heavy half first
  const int b = 2 * xcd + (s & 1);
  const int q0 = qt * 64;
  const int NT = 2 * qt + 2;                    // kv tiles of 32

  const short* kbase = k_rot + (size_t)b * CC * DD;
  const short* vbase = v_t + (size_t)b * DD * CC;

  // Q fragments: rows q0 + w*32 + rb*16 + li
  bf16x8 qf[2][8];
  #pragma unroll
  for (int rb = 0; rb < 2; ++rb) {
    const short* qb = q_rot + ((size_t)b * CC + q0 + w * 32 + rb * 16 + li) * DD;
    #pragma unroll
    for (int dc = 0; dc < 8; ++dc)
      qf[rb][dc] = *(const bf16x8*)(qb + dc * 32 + g * 8);
  }
  asm volatile("s_waitcnt vmcnt(0)" ::: "memory");
  __builtin_amdgcn_sched_barrier(0);

  f32x4 zero4 = {0.f, 0.f, 0.f, 0.f};
  f32x4 O[2][16];
  #pragma unroll
  for (int rb = 0; rb < 2; ++rb)
    #pragma unroll
    for (int i = 0; i < 16; ++i) O[rb][i] = zero4;
  float mrow[2][4], lrow[2][4];
  #pragma unroll
  for (int rb = 0; rb < 2; ++rb)
    #pragma unroll
    for (int r = 0; r < 4; ++r) { mrow[rb][r] = -__builtin_inff(); lrow[rb][r] = 0.f; }

  auto STAGE = [&](int buf, int kt) {           // 16 GLDS16 per wave
    const int k0s = kt * 32;
    #pragma unroll
    for (int i = 0; i < 8; ++i) {               // K tile: 16 chunks of 1KB
      int c = i * 2 + w;
      int row = 2 * c + (lane >> 5);
      int cb = (lane & 31) * 16;
      const char* src = (const char*)(kbase + (size_t)(k0s + row) * DD) +
                        (cb ^ ((row & 7) << 4));
      GLDS16(src, (char*)(&Ks[buf][0]) + c * 1024);
    }
    #pragma unroll
    for (int i = 0; i < 8; ++i) {               // V tile: 16 chunks of 1KB
      int c = i * 2 + w;
      int d = 16 * c + (lane >> 2);
      int cb = ((lane & 3) * 16) ^ ((d & 3) << 4);
      const char* src = (const char*)(vbase + (size_t)d * CC + k0s) + cb;
      GLDS16(src, (char*)(&Vs[buf][0]) + c * 1024);
    }
  };

  int cur = 0;
  STAGE(0, 0);
  for (int kt = 0; kt < NT; ++kt) {
    const int k0 = kt * 32;
    if (kt + 1 < NT) {
      STAGE(cur ^ 1, kt + 1);
      asm volatile("s_waitcnt vmcnt(16)" ::: "memory");   // current tile ready
    } else {
      asm volatile("s_waitcnt vmcnt(0)" ::: "memory");
    }
    __builtin_amdgcn_sched_barrier(0);
    __builtin_amdgcn_s_barrier();

    // S = Q K^T (scale folded into q); kf reused across row-blocks
    f32x4 S[2][2];
    #pragma unroll
    for (int rb = 0; rb < 2; ++rb) { S[rb][0] = zero4; S[rb][1] = zero4; }
    __builtin_amdgcn_s_setprio(1);
    #pragma unroll
    for (int dc = 0; dc < 8; ++dc) {
      #pragma unroll
      for (int nt = 0; nt < 2; ++nt) {
        int krow = nt * 16 + li;
        bf16x8 kf = *(const bf16x8*)((char*)(&Ks[cur][0]) + krow * 512 +
                                     (((dc * 64) + g * 16) ^ ((krow & 7) << 4)));
        S[0][nt] = __builtin_amdgcn_mfma_f32_16x16x32_bf16(qf[0][dc], kf, S[0][nt], 0, 0, 0);
        S[1][nt] = __builtin_amdgcn_mfma_f32_16x16x32_bf16(qf[1][dc], kf, S[1][nt], 0, 0, 0);
      }
    }
    __builtin_amdgcn_s_setprio(0);

    // causal mask only near the diagonal
    if (kt >= NT - 2) {
      #pragma unroll
      for (int rb = 0; rb < 2; ++rb)
        #pragma unroll
        for (int nt = 0; nt < 2; ++nt)
          #pragma unroll
          for (int r = 0; r < 4; ++r)
            if ((k0 + nt * 16 + li) > (q0 + w * 32 + rb * 16 + g * 4 + r))
              S[rb][nt][r] = -__builtin_inff();
    }

    // online softmax with defer-max (THR=8)
    float mxr[2][4];
    #pragma unroll
    for (int rb = 0; rb < 2; ++rb)
      #pragma unroll
      for (int r = 0; r < 4; ++r) {
        float mx = fmaxf(S[rb][0][r], S[rb][1][r]);
        mx = fmaxf(mx, __shfl_xor(mx, 1));
        mx = fmaxf(mx, __shfl_xor(mx, 2));
        mx = fmaxf(mx, __shfl_xor(mx, 4));
        mx = fmaxf(mx, __shfl_xor(mx, 8));
        mxr[rb][r] = mx;
      }
    int need = 0;
    #pragma unroll
    for (int rb = 0; rb < 2; ++rb)
      #pragma unroll
      for (int r = 0; r < 4; ++r) need |= (mxr[rb][r] > mrow[rb][r] + 8.f) ? 1 : 0;
    if (__any(need)) {
      #pragma unroll
      for (int rb = 0; rb < 2; ++rb)
        #pragma unroll
        for (int r = 0; r < 4; ++r) {
          float mnew = fmaxf(mrow[rb][r], mxr[rb][r]);
          float al = __expf(mrow[rb][r] - mnew);
          mrow[rb][r] = mnew;
          lrow[rb][r] *= al;
          #pragma unroll
          for (int dt2 = 0; dt2 < 16; ++dt2) O[rb][dt2][r] *= al;
        }
    }
    #pragma unroll
    for (int rb = 0; rb < 2; ++rb)
      #pragma unroll
      for (int r = 0; r < 4; ++r) {
        float rsum = 0.f;
        #pragma unroll
        for (int nt = 0; nt < 2; ++nt) {
          float pv = __expf(S[rb][nt][r] - mrow[rb][r]);
          S[rb][nt][r] = pv;
          rsum += pv;
        }
        rsum += __shfl_xor(rsum, 1);
        rsum += __shfl_xor(rsum, 2);
        rsum += __shfl_xor(rsum, 4);
        rsum += __shfl_xor(rsum, 8);
        lrow[rb][r] += rsum;
      }

    // P (C-layout) -> per-wave LDS -> A-frags
    #pragma unroll
    for (int rb = 0; rb < 2; ++rb)
      #pragma unroll
      for (int nt = 0; nt < 2; ++nt)
        #pragma unroll
        for (int r = 0; r < 4; ++r) {
          int pr = rb * 16 + g * 4 + r;
          *(short*)((char*)(&Ps[w][0]) + pr * 80 + (nt * 16 + li) * 2) =
              f2bf(S[rb][nt][r]);
        }

    // O += P V ; vf reused across row-blocks
    __builtin_amdgcn_s_setprio(1);
    bf16x8 pf0 = *(const bf16x8*)((char*)(&Ps[w][0]) + li * 80 + g * 16);
    bf16x8 pf1 = *(const bf16x8*)((char*)(&Ps[w][0]) + (16 + li) * 80 + g * 16);
    #pragma unroll
    for (int dt2 = 0; dt2 < 16; ++dt2) {
      int vrow = dt2 * 16 + li;
      bf16x8 vf = *(const bf16x8*)((char*)(&Vs[cur][0]) + vrow * 64 +
                                   ((g * 16) ^ ((vrow & 3) << 4)));
      O[0][dt2] = __builtin_amdgcn_mfma_f32_16x16x32_bf16(pf0, vf, O[0][dt2], 0, 0, 0);
      O[1][dt2] = __builtin_amdgcn_mfma_f32_16x16x32_bf16(pf1, vf, O[1][dt2], 0, 0, 0);
    }
    __builtin_amdgcn_s_setprio(0);
    __builtin_amdgcn_s_barrier();            // readers done before next restage
    cur ^= 1;
  } // kt

  // epilogue: normalize and store f32
  #pragma unroll
  for (int rb = 0; rb < 2; ++rb) {
    float invl[4];
    #pragma unroll
    for (int r = 0; r < 4; ++r) invl[r] = 1.f / lrow[rb][r];
    #pragma unroll
    for (int dt2 = 0; dt2 < 16; ++dt2)
      #pragma unroll
      for (int r = 0; r < 4; ++r) {
        int qr = q0 + w * 32 + rb * 16 + g * 4 + r;
        out[((size_t)b * CC + qr) * DD + dt2 * 16 + li] = O[rb][dt2][r] * invl[r];
      }
  }
}

// ---------------------------------------------------------------------------
extern "C" void kernel_launch(void* const* d_in, const int* in_sizes, int n_in,
                              void* d_out, int out_size, void* d_ws, size_t ws_size,
                              hipStream_t stream) {
  const float* x  = (const float*)d_in[0];
  const float* Wq = (const float*)d_in[1];
  const float* bq = (const float*)d_in[2];
  const float* Wk = (const float*)d_in[3];
  const float* bk = (const float*)d_in[4];
  const float* Wv = (const float*)d_in[5];
  const float* bv = (const float*)d_in[6];
  float* out = (float*)d_out;
  (void)in_sizes; (void)n_in; (void)out_size; (void)ws_size;

  // ws layout: cs 2MB | q_rot 16MB | k_rot 16MB | v_t 16MB | wb 384KB
  char* ws = (char*)d_ws;
  float2* cs   = (float2*)ws;
  short* q_rot = (short*)(ws + (2u << 20));
  short* k_rot = q_rot + (size_t)MM * DD;
  short* v_tr  = k_rot + (size_t)MM * DD;
  short* wb    = v_tr + (size_t)MM * DD;

  k_trig <<<1024, 256, 0, stream>>>(cs);
  k_wconv<<< 192, 256, 0, stream>>>(Wq, Wk, Wv, wb);
  k_qkv  <<< 512, 256, 0, stream>>>(x, wb, bq, bk, bv, cs, q_rot, k_rot, v_tr);
  k_attn <<< 512, 128, 0, stream>>>(q_rot, k_rot, v_tr, out);
}